// Round 2
// baseline (1076.608 us; speedup 1.0000x reference)
//
#include <hip/hip_runtime.h>

typedef __attribute__((ext_vector_type(8))) short short8;
typedef __attribute__((ext_vector_type(4))) float f32x4;
typedef unsigned short u16;
typedef unsigned int u32;

#define DEVI __device__ __forceinline__

// round-to-nearest-even f32 -> bf16 bits
DEVI u16 f2bf(float f) {
    union { float f; u32 u; } v; v.f = f;
    u32 r = v.u + 0x7FFFu + ((v.u >> 16) & 1u);
    return (u16)(r >> 16);
}

// ---------------- f32 -> bf16 bulk convert (vec4) ----------------
__global__ void cvt_bf16_kernel(const float* __restrict__ in, u16* __restrict__ out, int n4) {
    int i = blockIdx.x * blockDim.x + threadIdx.x;
    int stride = gridDim.x * blockDim.x;
    for (; i < n4; i += stride) {
        float4 v = reinterpret_cast<const float4*>(in)[i];
        ushort4 o;
        o.x = f2bf(v.x); o.y = f2bf(v.y); o.z = f2bf(v.z); o.w = f2bf(v.w);
        reinterpret_cast<ushort4*>(out)[i] = o;
    }
}

// ---------------- embed + pos + leaky1 -> bf16 A ----------------
__global__ __launch_bounds__(256)
void embed_leaky_kernel(const int* __restrict__ x, const float* __restrict__ emb,
                        const float* __restrict__ pos, const float* __restrict__ beta,
                        u16* __restrict__ Aout) {
    int tid = blockIdx.x * 256 + threadIdx.x;
    int b = tid >> 9;
    int h = tid & 511;
    float be = beta[h];
    float mem = 0.f;
    for (int t = 0; t < 128; ++t) {
        int idx = x[t * 32 + b];
        float v = emb[(size_t)idx * 512 + h] + pos[t * 512 + h];
        mem = be * mem + v;
        Aout[(size_t)(t * 32 + b) * 512 + h] = f2bf(mem);
    }
}

// ---------------- leaky over f32 input -> bf16 A ----------------
__global__ __launch_bounds__(256)
void leaky_bf16_kernel(const float* __restrict__ in, const float* __restrict__ beta,
                       u16* __restrict__ Aout) {
    int tid = blockIdx.x * 256 + threadIdx.x;
    int b = tid >> 9;
    int h = tid & 511;
    float be = beta[h];
    float mem = 0.f;
    for (int t = 0; t < 128; ++t) {
        size_t off = (size_t)(t * 32 + b) * 512 + h;
        mem = be * mem + in[off];
        Aout[off] = f2bf(mem);
    }
}

// ---------------- bf16 GEMM, C = A * B^T + bias (opt ReLU) ----------------
// A: [M, K] bf16 row-major (M % 128 == 0)
// B: [Npad, K] bf16 row-major (rows are output columns; Npad % 128 == 0)
// C: [M, N] f32
// VOCAB: col guard to N, nontemporal stores, bn-major XCD-chunked swizzle
template<bool RELU, bool VOCAB>
__global__ __launch_bounds__(256, 2)
void gemm_bt_128(const u16* __restrict__ A, const u16* __restrict__ B,
                 const float* __restrict__ bias, float* __restrict__ C,
                 int M, int N, int K, int tiles_m, int tiles_n) {
    __shared__ u16 As[128 * 32];
    __shared__ u16 Bs[128 * 32];
    const int tid = threadIdx.x;
    int bm, bn;
    if (VOCAB) {
        // bijective XCD-chunked remap, then bn-major (bm fastest)
        int nwg = tiles_m * tiles_n;
        int q = nwg >> 3, r = nwg & 7;
        int xcd = blockIdx.x & 7, idx = blockIdx.x >> 3;
        int wg = (xcd < r ? xcd * (q + 1) : r * (q + 1) + (xcd - r) * q) + idx;
        bn = wg / tiles_m;
        bm = wg % tiles_m;
    } else {
        bm = blockIdx.x / tiles_n;
        bn = blockIdx.x % tiles_n;
    }
    const int wv = tid >> 6;
    const int lane = tid & 63;
    const int wr = wv >> 1, wc = wv & 1;
    const int lrow = lane & 15;   // fragment row (A) / col (B) / C col
    const int kg = lane >> 4;     // k-group (8 elems each)

    f32x4 acc[4][4];
#pragma unroll
    for (int i = 0; i < 4; ++i)
#pragma unroll
        for (int j = 0; j < 4; ++j) acc[i][j] = (f32x4){0.f, 0.f, 0.f, 0.f};

    const size_t rowb = (size_t)K * 2;  // bytes per row
    const char* Ab = (const char*)A + (size_t)(bm * 128) * rowb;
    const char* Bb = (const char*)B + (size_t)(bn * 128) * rowb;

    for (int k0 = 0; k0 < K; k0 += 32) {
        // stage 128x32 bf16 tiles (8 KB each): 2 rounds x 256 lanes x 16 B
#pragma unroll
        for (int r = 0; r < 2; ++r) {
            int lin = (r * 256 + tid) * 16;  // byte offset within tile
            int row = lin >> 6;              // 64 B per row (32 bf16)
            int cb = lin & 63;
            __builtin_amdgcn_global_load_lds(
                (const __attribute__((address_space(1))) void*)(Ab + (size_t)row * rowb + (k0 << 1) + cb),
                (__attribute__((address_space(3))) void*)((char*)As + lin), 16, 0, 0);
            __builtin_amdgcn_global_load_lds(
                (const __attribute__((address_space(1))) void*)(Bb + (size_t)row * rowb + (k0 << 1) + cb),
                (__attribute__((address_space(3))) void*)((char*)Bs + lin), 16, 0, 0);
        }
        __syncthreads();

        short8 a[4], b[4];
#pragma unroll
        for (int mi = 0; mi < 4; ++mi)
            a[mi] = *(const short8*)&As[(wr * 64 + mi * 16 + lrow) * 32 + kg * 8];
#pragma unroll
        for (int ni = 0; ni < 4; ++ni)
            b[ni] = *(const short8*)&Bs[(wc * 64 + ni * 16 + lrow) * 32 + kg * 8];
#pragma unroll
        for (int mi = 0; mi < 4; ++mi)
#pragma unroll
            for (int ni = 0; ni < 4; ++ni)
                acc[mi][ni] = __builtin_amdgcn_mfma_f32_16x16x32_bf16(a[mi], b[ni], acc[mi][ni], 0, 0, 0);
        __syncthreads();
    }

    // epilogue: C/D layout col = lane&15, row = (lane>>4)*4 + j
#pragma unroll
    for (int ni = 0; ni < 4; ++ni) {
        int col = bn * 128 + wc * 64 + ni * 16 + lrow;
        if (VOCAB && col >= N) continue;
        float bv = bias[col];
#pragma unroll
        for (int mi = 0; mi < 4; ++mi) {
            f32x4 v = acc[mi][ni];
#pragma unroll
            for (int j = 0; j < 4; ++j) {
                int row = bm * 128 + wr * 64 + mi * 16 + kg * 4 + j;
                float o = v[j] + bv;
                if (RELU) o = fmaxf(o, 0.f);
                if (VOCAB)
                    __builtin_nontemporal_store(o, &C[(size_t)row * N + col]);
                else
                    C[(size_t)row * N + col] = o;
            }
        }
    }
}

extern "C" void kernel_launch(void* const* d_in, const int* in_sizes, int n_in,
                              void* d_out, int out_size, void* d_ws, size_t ws_size,
                              hipStream_t stream) {
    const int* x    = (const int*)d_in[0];
    const float* emb = (const float*)d_in[1];
    const float* pos = (const float*)d_in[2];
    const float* b1 = (const float*)d_in[3];
    const float* b2 = (const float*)d_in[4];
    const float* b3 = (const float*)d_in[5];
    const float* w2 = (const float*)d_in[6];
    const float* fb2 = (const float*)d_in[7];
    const float* w3 = (const float*)d_in[8];
    const float* fb3 = (const float*)d_in[9];
    const float* wo = (const float*)d_in[10];
    const float* fbo = (const float*)d_in[11];
    float* out = (float*)d_out;

    const int V = 50257, Vpad = 50304;  // Vpad = 393*128

    // workspace layout
    char* p = (char*)d_ws;
    u16* WO = (u16*)p;  p += (size_t)Vpad * 512 * 2;   // 51.5 MB
    u16* W2 = (u16*)p;  p += (size_t)512 * 512 * 2;
    u16* W3 = (u16*)p;  p += (size_t)512 * 512 * 2;
    u16* Abf = (u16*)p; p += (size_t)4096 * 512 * 2;   // bf16 activations [4096,512]
    float* Hb = (float*)p;                             // f32 activations [4096,512]

    // weight conversions f32 -> bf16
    cvt_bf16_kernel<<<dim3(2048), dim3(256), 0, stream>>>(wo, WO, V * 512 / 4);
    cvt_bf16_kernel<<<dim3(256), dim3(256), 0, stream>>>(w2, W2, 512 * 512 / 4);
    cvt_bf16_kernel<<<dim3(256), dim3(256), 0, stream>>>(w3, W3, 512 * 512 / 4);

    // embed + pos + leaky1 -> Abf
    embed_leaky_kernel<<<dim3(64), dim3(256), 0, stream>>>(x, emb, pos, b1, Abf);

    // fc2 + relu -> Hb
    gemm_bt_128<true, false><<<dim3(32 * 4), dim3(256), 0, stream>>>(Abf, W2, fb2, Hb, 4096, 512, 512, 32, 4);
    // leaky2 -> Abf
    leaky_bf16_kernel<<<dim3(64), dim3(256), 0, stream>>>(Hb, b2, Abf);
    // fc3 + relu -> Hb
    gemm_bt_128<true, false><<<dim3(32 * 4), dim3(256), 0, stream>>>(Abf, W3, fb3, Hb, 4096, 512, 512, 32, 4);
    // leaky3 -> Abf
    leaky_bf16_kernel<<<dim3(64), dim3(256), 0, stream>>>(Hb, b3, Abf);
    // vocab projection -> out (bn-major + XCD swizzle + NT stores)
    gemm_bt_128<false, true><<<dim3(32 * 393), dim3(256), 0, stream>>>(Abf, WO, fbo, out, 4096, V, 512, 32, 393);
}

// Round 3
// 557.443 us; speedup vs baseline: 1.9313x; 1.9313x over previous
//
#include <hip/hip_runtime.h>

typedef __attribute__((ext_vector_type(8))) short short8;
typedef __attribute__((ext_vector_type(4))) float f32x4;
typedef unsigned short u16;
typedef unsigned int u32;

#define DEVI __device__ __forceinline__

// round-to-nearest-even f32 -> bf16 bits
DEVI u16 f2bf(float f) {
    union { float f; u32 u; } v; v.f = f;
    u32 r = v.u + 0x7FFFu + ((v.u >> 16) & 1u);
    return (u16)(r >> 16);
}

// ---------------- f32 -> bf16 bulk convert (vec4) ----------------
__global__ void cvt_bf16_kernel(const float* __restrict__ in, u16* __restrict__ out, int n4) {
    int i = blockIdx.x * blockDim.x + threadIdx.x;
    int stride = gridDim.x * blockDim.x;
    for (; i < n4; i += stride) {
        float4 v = reinterpret_cast<const float4*>(in)[i];
        ushort4 o;
        o.x = f2bf(v.x); o.y = f2bf(v.y); o.z = f2bf(v.z); o.w = f2bf(v.w);
        reinterpret_cast<ushort4*>(out)[i] = o;
    }
}

// ---------------- embed + pos + leaky1 -> bf16 A ----------------
__global__ __launch_bounds__(256)
void embed_leaky_kernel(const int* __restrict__ x, const float* __restrict__ emb,
                        const float* __restrict__ pos, const float* __restrict__ beta,
                        u16* __restrict__ Aout) {
    int tid = blockIdx.x * 256 + threadIdx.x;
    int b = tid >> 9;
    int h = tid & 511;
    float be = beta[h];
    float mem = 0.f;
    for (int t = 0; t < 128; ++t) {
        int idx = x[t * 32 + b];
        float v = emb[(size_t)idx * 512 + h] + pos[t * 512 + h];
        mem = be * mem + v;
        Aout[(size_t)(t * 32 + b) * 512 + h] = f2bf(mem);
    }
}

// ---------------- leaky over f32 input -> bf16 A ----------------
__global__ __launch_bounds__(256)
void leaky_bf16_kernel(const float* __restrict__ in, const float* __restrict__ beta,
                       u16* __restrict__ Aout) {
    int tid = blockIdx.x * 256 + threadIdx.x;
    int b = tid >> 9;
    int h = tid & 511;
    float be = beta[h];
    float mem = 0.f;
    for (int t = 0; t < 128; ++t) {
        size_t off = (size_t)(t * 32 + b) * 512 + h;
        mem = be * mem + in[off];
        Aout[off] = f2bf(mem);
    }
}

// ---------------- bf16 GEMM, C = A * B^T + bias (opt ReLU) ----------------
// A: [M, K] bf16 row-major (M % 128 == 0)
// B: [Npad, K] bf16 row-major (rows are output columns; Npad % 128 == 0)
// C: [M, N] f32
// Epilogue: LDS-transposed, wave-contiguous 256B caching stores.
// VOCAB: col guard to N, bijective XCD-chunked bm-major swizzle.
template<bool RELU, bool VOCAB>
__global__ __launch_bounds__(256, 2)
void gemm_bt_128(const u16* __restrict__ A, const u16* __restrict__ B,
                 const float* __restrict__ bias, float* __restrict__ C,
                 int M, int N, int K, int tiles_m, int tiles_n) {
    __shared__ alignas(16) char smem[32 * 132 * 4];  // 16896 B, aliased
    u16* As = (u16*)smem;                 // 8 KB
    u16* Bs = (u16*)(smem + 8192);        // 8 KB
    float* Ep = (float*)smem;             // 32x132 f32 epilogue staging

    const int tid = threadIdx.x;
    int bm, bn;
    if (VOCAB) {
        // bijective XCD-chunked remap (contiguous wg chunk per XCD), bm-major
        int nwg = tiles_m * tiles_n;
        int q = nwg >> 3, r = nwg & 7;
        int xcd = blockIdx.x & 7, idx = blockIdx.x >> 3;
        int wg = (xcd < r ? xcd * (q + 1) : r * (q + 1) + (xcd - r) * q) + idx;
        bm = wg / tiles_n;
        bn = wg % tiles_n;
    } else {
        bm = blockIdx.x / tiles_n;
        bn = blockIdx.x % tiles_n;
    }
    const int wv = tid >> 6;
    const int lane = tid & 63;
    const int wr = wv >> 1, wc = wv & 1;
    const int lrow = lane & 15;   // fragment row (A) / col (B) / C col
    const int kg = lane >> 4;     // k-group (8 elems each)

    f32x4 acc[4][4];
#pragma unroll
    for (int i = 0; i < 4; ++i)
#pragma unroll
        for (int j = 0; j < 4; ++j) acc[i][j] = (f32x4){0.f, 0.f, 0.f, 0.f};

    const size_t rowb = (size_t)K * 2;  // bytes per row
    const char* Ab = (const char*)A + (size_t)(bm * 128) * rowb;
    const char* Bb = (const char*)B + (size_t)(bn * 128) * rowb;

    for (int k0 = 0; k0 < K; k0 += 32) {
#pragma unroll
        for (int r = 0; r < 2; ++r) {
            int lin = (r * 256 + tid) * 16;  // byte offset within tile
            int row = lin >> 6;              // 64 B per row (32 bf16)
            int cb = lin & 63;
            __builtin_amdgcn_global_load_lds(
                (const __attribute__((address_space(1))) void*)(Ab + (size_t)row * rowb + (k0 << 1) + cb),
                (__attribute__((address_space(3))) void*)((char*)As + lin), 16, 0, 0);
            __builtin_amdgcn_global_load_lds(
                (const __attribute__((address_space(1))) void*)(Bb + (size_t)row * rowb + (k0 << 1) + cb),
                (__attribute__((address_space(3))) void*)((char*)Bs + lin), 16, 0, 0);
        }
        __syncthreads();

        short8 a[4], b[4];
#pragma unroll
        for (int mi = 0; mi < 4; ++mi)
            a[mi] = *(const short8*)&As[(wr * 64 + mi * 16 + lrow) * 32 + kg * 8];
#pragma unroll
        for (int ni = 0; ni < 4; ++ni)
            b[ni] = *(const short8*)&Bs[(wc * 64 + ni * 16 + lrow) * 32 + kg * 8];
#pragma unroll
        for (int mi = 0; mi < 4; ++mi)
#pragma unroll
            for (int ni = 0; ni < 4; ++ni)
                acc[mi][ni] = __builtin_amdgcn_mfma_f32_16x16x32_bf16(a[mi], b[ni], acc[mi][ni], 0, 0, 0);
        __syncthreads();
    }

    // bias per lane-fragment-col (guarded for vocab tail tile)
    float bv[4];
#pragma unroll
    for (int ni = 0; ni < 4; ++ni) {
        int col = bn * 128 + wc * 64 + ni * 16 + lrow;
        bv[ni] = (!VOCAB || col < N) ? bias[col] : 0.f;
    }

    // Epilogue: 4 chunks of 32 rows x 128 cols via LDS, wave-contiguous stores.
    // acc C/D: col = lrow (+16*ni +64*wc), row(frag) = kg*4 + j.
    // chunk-local row r' = wr*16 + kg*4 + j; global row = bm*128 + (r'>>4)*64 + mi*16 + (r'&15)
#pragma unroll
    for (int mi = 0; mi < 4; ++mi) {
#pragma unroll
        for (int ni = 0; ni < 4; ++ni) {
            int c = wc * 64 + ni * 16 + lrow;
            f32x4 v = acc[mi][ni];
#pragma unroll
            for (int j = 0; j < 4; ++j) {
                float o = v[j] + bv[ni];
                if (RELU) o = fmaxf(o, 0.f);
                Ep[(wr * 16 + kg * 4 + j) * 132 + c] = o;
            }
        }
        __syncthreads();
        // store: wave wv owns chunk-local rows wv*8 .. wv*8+7; 2 x 256B per row
#pragma unroll
        for (int rr = 0; rr < 8; ++rr) {
            int rl = wv * 8 + rr;
            int grow = bm * 128 + (rl >> 4) * 64 + mi * 16 + (rl & 15);
            size_t base = (size_t)grow * N + bn * 128;
#pragma unroll
            for (int h = 0; h < 2; ++h) {
                int c = h * 64 + lane;
                float v = Ep[rl * 132 + c];
                if (!VOCAB || (bn * 128 + c) < N) C[base + c] = v;
            }
        }
        if (mi < 3) __syncthreads();
    }
}

extern "C" void kernel_launch(void* const* d_in, const int* in_sizes, int n_in,
                              void* d_out, int out_size, void* d_ws, size_t ws_size,
                              hipStream_t stream) {
    const int* x    = (const int*)d_in[0];
    const float* emb = (const float*)d_in[1];
    const float* pos = (const float*)d_in[2];
    const float* b1 = (const float*)d_in[3];
    const float* b2 = (const float*)d_in[4];
    const float* b3 = (const float*)d_in[5];
    const float* w2 = (const float*)d_in[6];
    const float* fb2 = (const float*)d_in[7];
    const float* w3 = (const float*)d_in[8];
    const float* fb3 = (const float*)d_in[9];
    const float* wo = (const float*)d_in[10];
    const float* fbo = (const float*)d_in[11];
    float* out = (float*)d_out;

    const int V = 50257, Vpad = 50304;  // Vpad = 393*128

    // workspace layout
    char* p = (char*)d_ws;
    u16* WO = (u16*)p;  p += (size_t)Vpad * 512 * 2;   // 51.5 MB
    u16* W2 = (u16*)p;  p += (size_t)512 * 512 * 2;
    u16* W3 = (u16*)p;  p += (size_t)512 * 512 * 2;
    u16* Abf = (u16*)p; p += (size_t)4096 * 512 * 2;   // bf16 activations [4096,512]
    float* Hb = (float*)p;                             // f32 activations [4096,512]

    // weight conversions f32 -> bf16
    cvt_bf16_kernel<<<dim3(2048), dim3(256), 0, stream>>>(wo, WO, V * 512 / 4);
    cvt_bf16_kernel<<<dim3(256), dim3(256), 0, stream>>>(w2, W2, 512 * 512 / 4);
    cvt_bf16_kernel<<<dim3(256), dim3(256), 0, stream>>>(w3, W3, 512 * 512 / 4);

    // embed + pos + leaky1 -> Abf
    embed_leaky_kernel<<<dim3(64), dim3(256), 0, stream>>>(x, emb, pos, b1, Abf);

    // fc2 + relu -> Hb
    gemm_bt_128<true, false><<<dim3(32 * 4), dim3(256), 0, stream>>>(Abf, W2, fb2, Hb, 4096, 512, 512, 32, 4);
    // leaky2 -> Abf
    leaky_bf16_kernel<<<dim3(64), dim3(256), 0, stream>>>(Hb, b2, Abf);
    // fc3 + relu -> Hb
    gemm_bt_128<true, false><<<dim3(32 * 4), dim3(256), 0, stream>>>(Abf, W3, fb3, Hb, 4096, 512, 512, 32, 4);
    // leaky3 -> Abf
    leaky_bf16_kernel<<<dim3(64), dim3(256), 0, stream>>>(Hb, b3, Abf);
    // vocab projection -> out (XCD-chunked bm-major + LDS-coalesced stores)
    gemm_bt_128<false, true><<<dim3(32 * 393), dim3(256), 0, stream>>>(Abf, WO, fbo, out, 4096, V, 512, 32, 393);
}